// Round 1
// baseline (728.701 us; speedup 1.0000x reference)
//
#include <hip/hip_runtime.h>
#include <hip/hip_bf16.h>

// Problem constants (match reference)
#define NN 100000
#define NG 512
#define H  128

typedef _Float16 half8 __attribute__((ext_vector_type(8)));
typedef float f32x4 __attribute__((ext_vector_type(4)));

// ---------------------------------------------------------------------------
// Merged: blocks [0,128) transpose+fp16-convert W1/W2; blocks [128,..) dst hist
__global__ __launch_bounds__(256) void k_wprep_hist(const float* __restrict__ W1,
                                                    const float* __restrict__ W2,
                                                    _Float16* __restrict__ Wt1,
                                                    _Float16* __restrict__ Wt2,
                                                    const int* __restrict__ dst,
                                                    int* __restrict__ deg, int E) {
    int bb = blockIdx.x;
    if (bb < 128) {
        const float* W = (bb < 64) ? W1 : W2;
        _Float16* Wt = (bb < 64) ? Wt1 : Wt2;
        int i = (bb & 63) * 256 + threadIdx.x;    // 0..16383
        int k = i >> 7, n = i & 127;
        Wt[n * 128 + k] = (_Float16)W[i];
        return;
    }
    int e = (bb - 128) * 256 + threadIdx.x;
    if (e < E) atomicAdd(&deg[dst[e]], 1);
}

// per-block exclusive scan (256 elems), partial sums to bsum
__global__ __launch_bounds__(256) void k_scan_block(const int* __restrict__ deg,
                                                    int* __restrict__ rowptr,
                                                    int* __restrict__ bsum, int n) {
    __shared__ int s[256];
    int tid = threadIdx.x;
    int i = blockIdx.x * 256 + tid;
    int v = (i < n) ? deg[i] : 0;
    s[tid] = v;
    __syncthreads();
    #pragma unroll
    for (int off = 1; off < 256; off <<= 1) {
        int t = (tid >= off) ? s[tid - off] : 0;
        __syncthreads();
        s[tid] += t;
        __syncthreads();
    }
    if (i < n) rowptr[i] = s[tid] - v;            // exclusive within block
    if (tid == 255) bsum[blockIdx.x] = s[255];    // block total
}

// scan of block sums (nb <= 512), single block
__global__ __launch_bounds__(512) void k_scan_top(int* __restrict__ bsum, int nb) {
    __shared__ int s[512];
    int tid = threadIdx.x;
    int v = (tid < nb) ? bsum[tid] : 0;
    s[tid] = v;
    __syncthreads();
    #pragma unroll
    for (int off = 1; off < 512; off <<= 1) {
        int t = (tid >= off) ? s[tid - off] : 0;
        __syncthreads();
        s[tid] += t;
        __syncthreads();
    }
    if (tid < nb) bsum[tid] = s[tid] - v;         // exclusive
}

// finalize: rowptr += block offset; cursor = rowptr; dinv = rsqrt(deg+1)
__global__ __launch_bounds__(256) void k_scan_fin(int* __restrict__ rowptr,
                                                  const int* __restrict__ bsum,
                                                  const int* __restrict__ deg,
                                                  int* __restrict__ cursor,
                                                  float* __restrict__ dinv,
                                                  int n, int E) {
    int i = blockIdx.x * 256 + threadIdx.x;
    if (i >= n) return;
    int r = rowptr[i] + bsum[i >> 8];
    rowptr[i] = r;
    cursor[i] = r;
    dinv[i] = rsqrtf((float)deg[i] + 1.0f);       // +1 self-loop; always > 0
    if (i == 0) rowptr[n] = E;
}

// ---------------------------------------------------------------------------
// Fused: blocks [0,nfb) fill CSR col; blocks [nfb,..) do GEMM1
// (tS = (x@W1)*dinv[row], fp16 out). LDS-free MFMA GEMM.
__global__ __launch_bounds__(256) void k_fill_gemm1(
        const int* __restrict__ src, const int* __restrict__ dst,
        int* __restrict__ cursor, int* __restrict__ col, int E, int nfb,
        const float* __restrict__ x, const _Float16* __restrict__ Wt1,
        const float* __restrict__ dinv, _Float16* __restrict__ tS, int n) {
    if ((int)blockIdx.x < nfb) {
        int e = blockIdx.x * 256 + threadIdx.x;
        if (e >= E) return;
        int d = dst[e];
        int pos = atomicAdd(&cursor[d], 1);
        col[pos] = src[e];
        return;
    }
    const int row0 = ((int)blockIdx.x - nfb) * 64;
    const int tid = threadIdx.x;
    const int w = tid >> 6, lane = tid & 63;
    const int l16 = lane & 15, quad = lane >> 4;
    const int Arow = row0 + w * 16 + l16;
    f32x4 acc[8] = {};
    #pragma unroll
    for (int kk = 0; kk < 4; ++kk) {
        half8 af;
        if (Arow < n) {
            const float* ap = x + (size_t)Arow * H + kk * 32 + quad * 8;
            float4 a0 = ((const float4*)ap)[0];
            float4 a1 = ((const float4*)ap)[1];
            af[0] = (_Float16)a0.x; af[1] = (_Float16)a0.y;
            af[2] = (_Float16)a0.z; af[3] = (_Float16)a0.w;
            af[4] = (_Float16)a1.x; af[5] = (_Float16)a1.y;
            af[6] = (_Float16)a1.z; af[7] = (_Float16)a1.w;
        } else {
            #pragma unroll
            for (int j = 0; j < 8; ++j) af[j] = (_Float16)0.0f;
        }
        #pragma unroll
        for (int nt = 0; nt < 8; ++nt) {
            half8 bf = *((const half8*)(Wt1 + (nt * 16 + l16) * H + kk * 32 + quad * 8));
            acc[nt] = __builtin_amdgcn_mfma_f32_16x16x32_f16(af, bf, acc[nt], 0, 0, 0);
        }
    }
    #pragma unroll
    for (int r = 0; r < 4; ++r) {
        int R = row0 + w * 16 + quad * 4 + r;
        if (R < n) {
            float sc = dinv[R];
            _Float16* crow = tS + (size_t)R * H + l16;
            #pragma unroll
            for (int nt = 0; nt < 8; ++nt)
                crow[nt * 16] = (_Float16)(acc[nt][r] * sc);
        }
    }
}

// ---------------------------------------------------------------------------
// GEMM2, LDS-free: tS2 = (h1 @ W2) * dinv[row]
__global__ __launch_bounds__(256) void k_gemm2(const _Float16* __restrict__ h1,
                                               const _Float16* __restrict__ Wt2,
                                               const float* __restrict__ dinv,
                                               _Float16* __restrict__ tS2, int n) {
    const int row0 = blockIdx.x * 64;
    const int tid = threadIdx.x;
    const int w = tid >> 6, lane = tid & 63;
    const int l16 = lane & 15, quad = lane >> 4;
    const int Arow = row0 + w * 16 + l16;
    f32x4 acc[8] = {};
    #pragma unroll
    for (int kk = 0; kk < 4; ++kk) {
        half8 af;
        if (Arow < n) {
            af = ((const half8*)(h1 + (size_t)Arow * H))[kk * 4 + quad];
        } else {
            #pragma unroll
            for (int j = 0; j < 8; ++j) af[j] = (_Float16)0.0f;
        }
        #pragma unroll
        for (int nt = 0; nt < 8; ++nt) {
            half8 bf = *((const half8*)(Wt2 + (nt * 16 + l16) * H + kk * 32 + quad * 8));
            acc[nt] = __builtin_amdgcn_mfma_f32_16x16x32_f16(af, bf, acc[nt], 0, 0, 0);
        }
    }
    #pragma unroll
    for (int r = 0; r < 4; ++r) {
        int R = row0 + w * 16 + quad * 4 + r;
        if (R < n) {
            float sc = dinv[R];
            _Float16* crow = tS2 + (size_t)R * H + l16;
            #pragma unroll
            for (int nt = 0; nt < 8; ++nt)
                crow[nt * 16] = (_Float16)(acc[nt][r] * sc);
        }
    }
}

// ---------------------------------------------------------------------------
// 16B row-fragment load that BYPASSES L1 (agent-scope relaxed atomic ->
// global_load_dwordx2 sc0). Used ONLY in gather2 (no store stream there).
__device__ __forceinline__ half8 ld_row16_nol1(const void* p) {
    union { unsigned long long u[2]; half8 h; } t;
    const unsigned long long* q = (const unsigned long long*)p;
    t.u[0] = __hip_atomic_load(q,     __ATOMIC_RELAXED, __HIP_MEMORY_SCOPE_AGENT);
    t.u[1] = __hip_atomic_load(q + 1, __ATOMIC_RELAXED, __HIP_MEMORY_SCOPE_AGENT);
    return t.h;
}

// Gather core, fp16 rows (256B). One wave per node; quarter-wave q handles
// edge slot 4g+q; lane loads 16B (8 halves) of the row.
// NEW (this round): masked 16-edge burst — up to 4 independent row loads per
// lane (16 rows in flight per wave, the whole typical node in one burst),
// exec-masked for partial bursts so no junk traffic. Collapses the previous
// {2-in-flight, drain, repeat} pattern (~5 round-trips/node) to ~3.
template <bool NOL1>
__device__ __forceinline__ void gather_rows_h(const _Float16* __restrict__ tS,
                                              const int* __restrict__ col,
                                              int node, int e0, int end,
                                              float acc[8]) {
    const int lane = threadIdx.x & 63;
    const int q = lane >> 4;
    const int l16 = lane & 15;
    const char* tSb = (const char*)tS;       // rows are 256B; 32-bit byte offsets
    const uint32_t fo = (uint32_t)(l16 << 4);
    float a0[8] = {}, a1[8] = {};
    if (q == 0) {                            // self-loop row (cached load)
        half8 v = *(const half8*)(tSb + (((uint32_t)node << 8) + fo));
        #pragma unroll
        for (int i = 0; i < 8; ++i) a0[i] = (float)v[i];
    }
    for (int base = e0; base < end; base += 64) {
        int ce = base + lane;
        int cidx = (ce < end) ? col[ce] : 0;
        int m = min(64, end - base);
        int ng = (m + 3) >> 2;               // groups of 4 edges (last may be partial)
        for (int g = 0; g < ng; g += 4) {
            int p0 = 4 * g + q, p1 = p0 + 4, p2 = p0 + 8, p3 = p0 + 12;
            int s0 = __shfl(cidx, p0), s1 = __shfl(cidx, p1);
            int s2 = __shfl(cidx, p2), s3 = __shfl(cidx, p3);
            half8 v0 = {}, v1 = {}, v2 = {}, v3 = {};
            if (NOL1) {
                if (p0 < m) v0 = ld_row16_nol1(tSb + (((uint32_t)s0 << 8) + fo));
                if (p1 < m) v1 = ld_row16_nol1(tSb + (((uint32_t)s1 << 8) + fo));
                if (p2 < m) v2 = ld_row16_nol1(tSb + (((uint32_t)s2 << 8) + fo));
                if (p3 < m) v3 = ld_row16_nol1(tSb + (((uint32_t)s3 << 8) + fo));
            } else {
                if (p0 < m) v0 = *(const half8*)(tSb + (((uint32_t)s0 << 8) + fo));
                if (p1 < m) v1 = *(const half8*)(tSb + (((uint32_t)s1 << 8) + fo));
                if (p2 < m) v2 = *(const half8*)(tSb + (((uint32_t)s2 << 8) + fo));
                if (p3 < m) v3 = *(const half8*)(tSb + (((uint32_t)s3 << 8) + fo));
            }
            #pragma unroll
            for (int i = 0; i < 8; ++i) {
                a0[i] += (float)v0[i];
                a1[i] += (float)v1[i];
                a0[i] += (float)v2[i];
                a1[i] += (float)v3[i];
            }
        }
    }
    #pragma unroll
    for (int i = 0; i < 8; ++i) {
        float t = a0[i] + a1[i];
        t += __shfl_xor(t, 16);
        t += __shfl_xor(t, 32);
        acc[i] = t;
    }
}

// gather layer 1: out (fp16) = relu(dinv[n]*(tS[n] + sum in-edges) + b)
__global__ __launch_bounds__(256) void k_gather1(const _Float16* __restrict__ tS,
                                                 const int* __restrict__ rowptr,
                                                 const int* __restrict__ col,
                                                 const float* __restrict__ dinv,
                                                 const float* __restrict__ b,
                                                 _Float16* __restrict__ out, int n) {
    int node = blockIdx.x * 4 + (threadIdx.x >> 6);
    int lane = threadIdx.x & 63;
    int q = lane >> 4, l16 = lane & 15;
    if (node >= n) return;
    int e0 = rowptr[node], end = rowptr[node + 1];
    float acc[8];
    gather_rows_h<false>(tS, col, node, e0, end, acc);
    if (q == 0) {
        float dn = dinv[node];
        const float4* b4 = (const float4*)b;
        float4 bb0 = b4[2 * l16], bb1 = b4[2 * l16 + 1];
        half8 hv;
        hv[0] = (_Float16)fmaxf(dn * acc[0] + bb0.x, 0.0f);
        hv[1] = (_Float16)fmaxf(dn * acc[1] + bb0.y, 0.0f);
        hv[2] = (_Float16)fmaxf(dn * acc[2] + bb0.z, 0.0f);
        hv[3] = (_Float16)fmaxf(dn * acc[3] + bb0.w, 0.0f);
        hv[4] = (_Float16)fmaxf(dn * acc[4] + bb1.x, 0.0f);
        hv[5] = (_Float16)fmaxf(dn * acc[5] + bb1.y, 0.0f);
        hv[6] = (_Float16)fmaxf(dn * acc[6] + bb1.z, 0.0f);
        hv[7] = (_Float16)fmaxf(dn * acc[7] + bb1.w, 0.0f);
        ((half8*)out)[(size_t)node * 16 + l16] = hv;
    }
}

// gather layer 2 fused with pool head: v = relu(...); pool[batch[n]] += dot(v, Wp)
// (cnt atomics removed — counts are recovered by binary search in final kernel)
__global__ __launch_bounds__(256) void k_gather2(const _Float16* __restrict__ tS,
                                                 const int* __restrict__ rowptr,
                                                 const int* __restrict__ col,
                                                 const float* __restrict__ dinv,
                                                 const float* __restrict__ b,
                                                 const float* __restrict__ Wp,
                                                 const int* __restrict__ batch,
                                                 float* __restrict__ pool, int n) {
    int node = blockIdx.x * 4 + (threadIdx.x >> 6);
    int lane = threadIdx.x & 63;
    int l16 = lane & 15;
    if (node >= n) return;
    int e0 = rowptr[node], end = rowptr[node + 1];
    float acc[8];
    gather_rows_h<true>(tS, col, node, e0, end, acc);
    float dn = dinv[node];
    const float4* b4 = (const float4*)b;
    const float4* w4 = (const float4*)Wp;
    float4 bb0 = b4[2 * l16], bb1 = b4[2 * l16 + 1];
    float4 wp0 = w4[2 * l16], wp1 = w4[2 * l16 + 1];
    float s = fmaxf(dn * acc[0] + bb0.x, 0.0f) * wp0.x +
              fmaxf(dn * acc[1] + bb0.y, 0.0f) * wp0.y +
              fmaxf(dn * acc[2] + bb0.z, 0.0f) * wp0.z +
              fmaxf(dn * acc[3] + bb0.w, 0.0f) * wp0.w +
              fmaxf(dn * acc[4] + bb1.x, 0.0f) * wp1.x +
              fmaxf(dn * acc[5] + bb1.y, 0.0f) * wp1.y +
              fmaxf(dn * acc[6] + bb1.z, 0.0f) * wp1.z +
              fmaxf(dn * acc[7] + bb1.w, 0.0f) * wp1.w;
    s += __shfl_xor(s, 1);
    s += __shfl_xor(s, 2);
    s += __shfl_xor(s, 4);
    s += __shfl_xor(s, 8);
    if (lane == 0) {
        int g = batch[node];
        atomicAdd(&pool[g], s);
    }
}

// ---------------------------------------------------------------------------
// batch is sorted: per-graph node counts via binary search (replaces 100K
// float atomics previously done in gather2).
__global__ __launch_bounds__(256) void final_out_kernel(const float* __restrict__ pool,
                                                        const int* __restrict__ batch,
                                                        const float* __restrict__ bp,
                                                        float* __restrict__ out, int g) {
    int i = blockIdx.x * 256 + threadIdx.x;
    if (i >= g) return;
    int lo = 0, hi = NN;
    while (lo < hi) { int mid = (lo + hi) >> 1; if (batch[mid] < i) lo = mid + 1; else hi = mid; }
    int s0 = lo;
    hi = NN;
    while (lo < hi) { int mid = (lo + hi) >> 1; if (batch[mid] < i + 1) lo = mid + 1; else hi = mid; }
    float c = (float)(lo - s0);
    out[i] = pool[i] / fmaxf(c, 1.0f) + bp[0];
}

// ---------------------------------------------------------------------------
extern "C" void kernel_launch(void* const* d_in, const int* in_sizes, int n_in,
                              void* d_out, int out_size, void* d_ws, size_t ws_size,
                              hipStream_t stream) {
    const float* x     = (const float*)d_in[0];
    const int*   ei    = (const int*)d_in[1];   // [2, E]: src = ei[0:E], dst = ei[E:2E]
    const int*   batch = (const int*)d_in[2];
    const float* W1    = (const float*)d_in[3];
    const float* b1    = (const float*)d_in[4];
    const float* W2    = (const float*)d_in[5];
    const float* b2    = (const float*)d_in[6];
    const float* Wp    = (const float*)d_in[7];
    const float* bp    = (const float*)d_in[8];
    float* out = (float*)d_out;

    const int E = in_sizes[1] / 2;   // 1,600,000
    const int* src = ei;
    const int* dst = ei + E;

    // workspace layout
    const size_t BUFH = (size_t)NN * H * sizeof(_Float16);   // 25.6 MB
    const size_t NI   = 401408;                               // >= (NN+1)*4, 4KB-mult
    char* ws = (char*)d_ws;
    size_t off = 0;
    _Float16* tS   = (_Float16*)(ws + off); off += BUFH;     // GEMM1 out (fp16)
    _Float16* h1   = (_Float16*)(ws + off); off += BUFH;     // layer-1 acts (fp16)
    _Float16* tS2  = (_Float16*)(ws + off); off += BUFH;     // GEMM2 out (fp16)
    int*      deg  = (int*)     (ws + off); off += NI;
    int*   rowptr  = (int*)     (ws + off); off += NI;
    int*   cursor  = (int*)     (ws + off); off += NI;
    float*    dinv = (float*)   (ws + off); off += NI;
    int*      col  = (int*)     (ws + off); off += ((size_t)E * 4 + 4095) / 4096 * 4096;
    _Float16* Wt1  = (_Float16*)(ws + off); off += 32768;
    _Float16* Wt2  = (_Float16*)(ws + off); off += 32768;
    int*      bsum = (int*)     (ws + off); off += 4096;
    float*    pool = (float*)   (ws + off); off += 2048;

    const int NB  = (NN + 255) / 256;   // 391 scan blocks
    const int NFB = (E + 255) / 256;    // 6250 fill/hist blocks
    const int NGB = (NN + 63) / 64;     // 1563 gemm blocks

    // --- weights prep ∥ histogram (one dispatch), then scans ---
    hipMemsetAsync(deg, 0, NN * sizeof(int), stream);
    hipMemsetAsync(pool, 0, 2048, stream);
    k_wprep_hist<<<128 + NFB, 256, 0, stream>>>(W1, W2, Wt1, Wt2, dst, deg, E);
    k_scan_block<<<NB, 256, 0, stream>>>(deg, rowptr, bsum, NN);
    k_scan_top<<<1, 512, 0, stream>>>(bsum, NB);
    k_scan_fin<<<NB, 256, 0, stream>>>(rowptr, bsum, deg, cursor, dinv, NN, E);

    // --- fill CSR  ∥  GEMM1 (one dispatch, disjoint block ranges) ---
    k_fill_gemm1<<<NFB + NGB, 256, 0, stream>>>(src, dst, cursor, col, E, NFB,
                                                x, Wt1, dinv, tS, NN);

    // --- layer 1: gather (wave/node) then LDS-free MFMA GEMM2 ---
    k_gather1<<<(NN + 3) / 4, 256, 0, stream>>>(tS, rowptr, col, dinv, b1, h1, NN);
    k_gemm2<<<NGB, 256, 0, stream>>>(h1, Wt2, dinv, tS2, NN);

    // --- layer 2 gather + pool head ---
    k_gather2<<<(NN + 3) / 4, 256, 0, stream>>>(tS2, rowptr, col, dinv, b2, Wp,
                                                batch, pool, NN);

    // --- head ---
    final_out_kernel<<<(NG + 255) / 256, 256, 0, stream>>>(pool, batch, bp, out, NG);
}

// Round 2
// 704.320 us; speedup vs baseline: 1.0346x; 1.0346x over previous
//
#include <hip/hip_runtime.h>
#include <hip/hip_bf16.h>

// Problem constants (match reference)
#define NN 100000
#define NG 512
#define H  128

typedef _Float16 half8 __attribute__((ext_vector_type(8)));
typedef float f32x4 __attribute__((ext_vector_type(4)));

// ---------------------------------------------------------------------------
// Merged: blocks [0,128) transpose+fp16-convert W1/W2; blocks [128,..) dst hist
__global__ __launch_bounds__(256) void k_wprep_hist(const float* __restrict__ W1,
                                                    const float* __restrict__ W2,
                                                    _Float16* __restrict__ Wt1,
                                                    _Float16* __restrict__ Wt2,
                                                    const int* __restrict__ dst,
                                                    int* __restrict__ deg, int E) {
    int bb = blockIdx.x;
    if (bb < 128) {
        const float* W = (bb < 64) ? W1 : W2;
        _Float16* Wt = (bb < 64) ? Wt1 : Wt2;
        int i = (bb & 63) * 256 + threadIdx.x;    // 0..16383
        int k = i >> 7, n = i & 127;
        Wt[n * 128 + k] = (_Float16)W[i];
        return;
    }
    int e = (bb - 128) * 256 + threadIdx.x;
    if (e < E) atomicAdd(&deg[dst[e]], 1);
}

// per-block exclusive scan (256 elems), partial sums to bsum
__global__ __launch_bounds__(256) void k_scan_block(const int* __restrict__ deg,
                                                    int* __restrict__ rowptr,
                                                    int* __restrict__ bsum, int n) {
    __shared__ int s[256];
    int tid = threadIdx.x;
    int i = blockIdx.x * 256 + tid;
    int v = (i < n) ? deg[i] : 0;
    s[tid] = v;
    __syncthreads();
    #pragma unroll
    for (int off = 1; off < 256; off <<= 1) {
        int t = (tid >= off) ? s[tid - off] : 0;
        __syncthreads();
        s[tid] += t;
        __syncthreads();
    }
    if (i < n) rowptr[i] = s[tid] - v;            // exclusive within block
    if (tid == 255) bsum[blockIdx.x] = s[255];    // block total
}

// scan of block sums (nb <= 512), single block
__global__ __launch_bounds__(512) void k_scan_top(int* __restrict__ bsum, int nb) {
    __shared__ int s[512];
    int tid = threadIdx.x;
    int v = (tid < nb) ? bsum[tid] : 0;
    s[tid] = v;
    __syncthreads();
    #pragma unroll
    for (int off = 1; off < 512; off <<= 1) {
        int t = (tid >= off) ? s[tid - off] : 0;
        __syncthreads();
        s[tid] += t;
        __syncthreads();
    }
    if (tid < nb) bsum[tid] = s[tid] - v;         // exclusive
}

// finalize: rowptr += block offset; cursor = rowptr; dinv = rsqrt(deg+1)
__global__ __launch_bounds__(256) void k_scan_fin(int* __restrict__ rowptr,
                                                  const int* __restrict__ bsum,
                                                  const int* __restrict__ deg,
                                                  int* __restrict__ cursor,
                                                  float* __restrict__ dinv,
                                                  int n, int E) {
    int i = blockIdx.x * 256 + threadIdx.x;
    if (i >= n) return;
    int r = rowptr[i] + bsum[i >> 8];
    rowptr[i] = r;
    cursor[i] = r;
    dinv[i] = rsqrtf((float)deg[i] + 1.0f);       // +1 self-loop; always > 0
    if (i == 0) rowptr[n] = E;
}

// ---------------------------------------------------------------------------
// Fused: blocks [0,nfb) fill CSR col; blocks [nfb,..) do GEMM1
// (tS = (x@W1)*dinv[row], fp16 out). LDS-free MFMA GEMM.
__global__ __launch_bounds__(256) void k_fill_gemm1(
        const int* __restrict__ src, const int* __restrict__ dst,
        int* __restrict__ cursor, int* __restrict__ col, int E, int nfb,
        const float* __restrict__ x, const _Float16* __restrict__ Wt1,
        const float* __restrict__ dinv, _Float16* __restrict__ tS, int n) {
    if ((int)blockIdx.x < nfb) {
        int e = blockIdx.x * 256 + threadIdx.x;
        if (e >= E) return;
        int d = dst[e];
        int pos = atomicAdd(&cursor[d], 1);
        col[pos] = src[e];
        return;
    }
    const int row0 = ((int)blockIdx.x - nfb) * 64;
    const int tid = threadIdx.x;
    const int w = tid >> 6, lane = tid & 63;
    const int l16 = lane & 15, quad = lane >> 4;
    const int Arow = row0 + w * 16 + l16;
    f32x4 acc[8] = {};
    #pragma unroll
    for (int kk = 0; kk < 4; ++kk) {
        half8 af;
        if (Arow < n) {
            const float* ap = x + (size_t)Arow * H + kk * 32 + quad * 8;
            float4 a0 = ((const float4*)ap)[0];
            float4 a1 = ((const float4*)ap)[1];
            af[0] = (_Float16)a0.x; af[1] = (_Float16)a0.y;
            af[2] = (_Float16)a0.z; af[3] = (_Float16)a0.w;
            af[4] = (_Float16)a1.x; af[5] = (_Float16)a1.y;
            af[6] = (_Float16)a1.z; af[7] = (_Float16)a1.w;
        } else {
            #pragma unroll
            for (int j = 0; j < 8; ++j) af[j] = (_Float16)0.0f;
        }
        #pragma unroll
        for (int nt = 0; nt < 8; ++nt) {
            half8 bf = *((const half8*)(Wt1 + (nt * 16 + l16) * H + kk * 32 + quad * 8));
            acc[nt] = __builtin_amdgcn_mfma_f32_16x16x32_f16(af, bf, acc[nt], 0, 0, 0);
        }
    }
    #pragma unroll
    for (int r = 0; r < 4; ++r) {
        int R = row0 + w * 16 + quad * 4 + r;
        if (R < n) {
            float sc = dinv[R];
            _Float16* crow = tS + (size_t)R * H + l16;
            #pragma unroll
            for (int nt = 0; nt < 8; ++nt)
                crow[nt * 16] = (_Float16)(acc[nt][r] * sc);
        }
    }
}

// ---------------------------------------------------------------------------
// GEMM2, LDS-free: tS2 = (h1 @ W2) * dinv[row]
__global__ __launch_bounds__(256) void k_gemm2(const _Float16* __restrict__ h1,
                                               const _Float16* __restrict__ Wt2,
                                               const float* __restrict__ dinv,
                                               _Float16* __restrict__ tS2, int n) {
    const int row0 = blockIdx.x * 64;
    const int tid = threadIdx.x;
    const int w = tid >> 6, lane = tid & 63;
    const int l16 = lane & 15, quad = lane >> 4;
    const int Arow = row0 + w * 16 + l16;
    f32x4 acc[8] = {};
    #pragma unroll
    for (int kk = 0; kk < 4; ++kk) {
        half8 af;
        if (Arow < n) {
            af = ((const half8*)(h1 + (size_t)Arow * H))[kk * 4 + quad];
        } else {
            #pragma unroll
            for (int j = 0; j < 8; ++j) af[j] = (_Float16)0.0f;
        }
        #pragma unroll
        for (int nt = 0; nt < 8; ++nt) {
            half8 bf = *((const half8*)(Wt2 + (nt * 16 + l16) * H + kk * 32 + quad * 8));
            acc[nt] = __builtin_amdgcn_mfma_f32_16x16x32_f16(af, bf, acc[nt], 0, 0, 0);
        }
    }
    #pragma unroll
    for (int r = 0; r < 4; ++r) {
        int R = row0 + w * 16 + quad * 4 + r;
        if (R < n) {
            float sc = dinv[R];
            _Float16* crow = tS2 + (size_t)R * H + l16;
            #pragma unroll
            for (int nt = 0; nt < 8; ++nt)
                crow[nt * 16] = (_Float16)(acc[nt][r] * sc);
        }
    }
}

// ---------------------------------------------------------------------------
// 16B row-fragment load that BYPASSES L1 (agent-scope relaxed atomic ->
// global_load_dwordx2 sc0). Used ONLY in gather2 (no store stream there).
__device__ __forceinline__ half8 ld_row16_nol1(const void* p) {
    union { unsigned long long u[2]; half8 h; } t;
    const unsigned long long* q = (const unsigned long long*)p;
    t.u[0] = __hip_atomic_load(q,     __ATOMIC_RELAXED, __HIP_MEMORY_SCOPE_AGENT);
    t.u[1] = __hip_atomic_load(q + 1, __ATOMIC_RELAXED, __HIP_MEMORY_SCOPE_AGENT);
    return t.h;
}

// ---------------------------------------------------------------------------
// PAIR gather core: one wave processes nodes nA and nB=nA+1. Their CSR edge
// lists are CONTIGUOUS ([e0,e2), boundary e1), so ONE prelude (rowptr fetch +
// col chunk load) covers both nodes (~32 edges avg) — halves the serial
// round-trip count per node and keeps the row-load pipe fed longer.
// Inner accumulate pattern is the round-0 proven one (unmasked 2-in-flight
// groups + tail). A/B routing: quarter-uniform branch on (edge_idx < e1) —
// boundary is crossed once per pair, so common-case cost stays 8 adds/row.
// After xor-16/32 reduce, every lane holds full sums for both nodes.
template <bool NOL1>
__device__ __forceinline__ void gather_pair_h(const _Float16* __restrict__ tS,
                                              const int* __restrict__ col,
                                              int nA, int nB, bool hasB,
                                              int e0, int e1, int e2,
                                              float accA[8], float accB[8]) {
    const int lane = threadIdx.x & 63;
    const int q = lane >> 4;
    const int l16 = lane & 15;
    const char* tSb = (const char*)tS;       // rows are 256B; 32-bit byte offsets
    const uint32_t fo = (uint32_t)(l16 << 4);
    float xA[8] = {}, xB[8] = {};
    if (q == 0) {                            // self-loop row A
        half8 v = *(const half8*)(tSb + (((uint32_t)nA << 8) + fo));
        #pragma unroll
        for (int i = 0; i < 8; ++i) xA[i] = (float)v[i];
    }
    if (q == 1 && hasB) {                    // self-loop row B
        half8 v = *(const half8*)(tSb + (((uint32_t)nB << 8) + fo));
        #pragma unroll
        for (int i = 0; i < 8; ++i) xB[i] = (float)v[i];
    }
    for (int base = e0; base < e2; base += 64) {
        int ce = base + lane;
        int cidx = (ce < e2) ? col[ce] : 0;
        int m = min(64, e2 - base);
        int nf = m >> 2;                     // full groups of 4 edges
        int g = 0;
        for (; g + 2 <= nf; g += 2) {
            int p0 = 4 * g + q, p1 = p0 + 4;
            int s0 = __shfl(cidx, p0);
            int s1 = __shfl(cidx, p1);
            half8 v0, v1;
            if (NOL1) {
                v0 = ld_row16_nol1(tSb + (((uint32_t)s0 << 8) + fo));
                v1 = ld_row16_nol1(tSb + (((uint32_t)s1 << 8) + fo));
            } else {
                v0 = *(const half8*)(tSb + (((uint32_t)s0 << 8) + fo));
                v1 = *(const half8*)(tSb + (((uint32_t)s1 << 8) + fo));
            }
            float f0[8], f1[8];
            #pragma unroll
            for (int i = 0; i < 8; ++i) { f0[i] = (float)v0[i]; f1[i] = (float)v1[i]; }
            if (base + p0 < e1) {
                #pragma unroll
                for (int i = 0; i < 8; ++i) xA[i] += f0[i];
            } else {
                #pragma unroll
                for (int i = 0; i < 8; ++i) xB[i] += f0[i];
            }
            if (base + p1 < e1) {
                #pragma unroll
                for (int i = 0; i < 8; ++i) xA[i] += f1[i];
            } else {
                #pragma unroll
                for (int i = 0; i < 8; ++i) xB[i] += f1[i];
            }
        }
        if (g < nf) {
            int p0 = 4 * g + q;
            int s0 = __shfl(cidx, p0);
            half8 v0 = NOL1 ? ld_row16_nol1(tSb + (((uint32_t)s0 << 8) + fo))
                            : *(const half8*)(tSb + (((uint32_t)s0 << 8) + fo));
            float f0[8];
            #pragma unroll
            for (int i = 0; i < 8; ++i) f0[i] = (float)v0[i];
            if (base + p0 < e1) {
                #pragma unroll
                for (int i = 0; i < 8; ++i) xA[i] += f0[i];
            } else {
                #pragma unroll
                for (int i = 0; i < 8; ++i) xB[i] += f0[i];
            }
        }
        int tail = m & 3;
        if (tail) {
            int p = 4 * nf + q;
            int s = __shfl(cidx, p);         // all lanes active here
            if (q < tail) {
                half8 v = NOL1 ? ld_row16_nol1(tSb + (((uint32_t)s << 8) + fo))
                               : *(const half8*)(tSb + (((uint32_t)s << 8) + fo));
                float f[8];
                #pragma unroll
                for (int i = 0; i < 8; ++i) f[i] = (float)v[i];
                if (base + p < e1) {
                    #pragma unroll
                    for (int i = 0; i < 8; ++i) xA[i] += f[i];
                } else {
                    #pragma unroll
                    for (int i = 0; i < 8; ++i) xB[i] += f[i];
                }
            }
        }
    }
    #pragma unroll
    for (int i = 0; i < 8; ++i) {
        float t = xA[i];
        t += __shfl_xor(t, 16);
        t += __shfl_xor(t, 32);
        accA[i] = t;
        float u = xB[i];
        u += __shfl_xor(u, 16);
        u += __shfl_xor(u, 32);
        accB[i] = u;
    }
}

// gather layer 1: out (fp16) = relu(dinv[n]*(tS[n] + sum in-edges) + b)
// One wave per NODE PAIR. Quarter 0 stores node A's row, quarter 1 node B's.
__global__ __launch_bounds__(256) void k_gather1(const _Float16* __restrict__ tS,
                                                 const int* __restrict__ rowptr,
                                                 const int* __restrict__ col,
                                                 const float* __restrict__ dinv,
                                                 const float* __restrict__ b,
                                                 _Float16* __restrict__ out, int n) {
    int widx = blockIdx.x * 4 + (threadIdx.x >> 6);
    int nA = widx * 2;
    if (nA >= n) return;
    int nB = nA + 1;
    bool hasB = (nB < n);
    int lane = threadIdx.x & 63;
    int q = lane >> 4, l16 = lane & 15;
    int e0 = rowptr[nA];
    int e1 = rowptr[nA + 1];
    int e2 = hasB ? rowptr[nA + 2] : e1;
    float accA[8], accB[8];
    gather_pair_h<false>(tS, col, nA, nB, hasB, e0, e1, e2, accA, accB);
    if (q <= 1) {
        int node = (q == 0) ? nA : nB;
        const float* acc = (q == 0) ? accA : accB;
        if (q == 0 || hasB) {
            float dn = dinv[node];
            const float4* b4 = (const float4*)b;
            float4 bb0 = b4[2 * l16], bb1 = b4[2 * l16 + 1];
            half8 hv;
            hv[0] = (_Float16)fmaxf(dn * acc[0] + bb0.x, 0.0f);
            hv[1] = (_Float16)fmaxf(dn * acc[1] + bb0.y, 0.0f);
            hv[2] = (_Float16)fmaxf(dn * acc[2] + bb0.z, 0.0f);
            hv[3] = (_Float16)fmaxf(dn * acc[3] + bb0.w, 0.0f);
            hv[4] = (_Float16)fmaxf(dn * acc[4] + bb1.x, 0.0f);
            hv[5] = (_Float16)fmaxf(dn * acc[5] + bb1.y, 0.0f);
            hv[6] = (_Float16)fmaxf(dn * acc[6] + bb1.z, 0.0f);
            hv[7] = (_Float16)fmaxf(dn * acc[7] + bb1.w, 0.0f);
            ((half8*)out)[(size_t)node * 16 + l16] = hv;
        }
    }
}

// gather layer 2 fused with pool head: v = relu(...); pool[batch[n]] += dot(v, Wp)
// One wave per NODE PAIR; both dots computed on all lanes (redundant, cheap),
// xor-reduced within 16-lane groups; lane 0 does the two pool atomics.
__global__ __launch_bounds__(256) void k_gather2(const _Float16* __restrict__ tS,
                                                 const int* __restrict__ rowptr,
                                                 const int* __restrict__ col,
                                                 const float* __restrict__ dinv,
                                                 const float* __restrict__ b,
                                                 const float* __restrict__ Wp,
                                                 const int* __restrict__ batch,
                                                 float* __restrict__ pool, int n) {
    int widx = blockIdx.x * 4 + (threadIdx.x >> 6);
    int nA = widx * 2;
    if (nA >= n) return;
    int nB = nA + 1;
    bool hasB = (nB < n);
    int lane = threadIdx.x & 63;
    int l16 = lane & 15;
    int e0 = rowptr[nA];
    int e1 = rowptr[nA + 1];
    int e2 = hasB ? rowptr[nA + 2] : e1;
    float accA[8], accB[8];
    gather_pair_h<true>(tS, col, nA, nB, hasB, e0, e1, e2, accA, accB);
    float dnA = dinv[nA];
    float dnB = hasB ? dinv[nB] : 0.0f;
    const float4* b4 = (const float4*)b;
    const float4* w4 = (const float4*)Wp;
    float4 bb0 = b4[2 * l16], bb1 = b4[2 * l16 + 1];
    float4 wp0 = w4[2 * l16], wp1 = w4[2 * l16 + 1];
    float sA = fmaxf(dnA * accA[0] + bb0.x, 0.0f) * wp0.x +
               fmaxf(dnA * accA[1] + bb0.y, 0.0f) * wp0.y +
               fmaxf(dnA * accA[2] + bb0.z, 0.0f) * wp0.z +
               fmaxf(dnA * accA[3] + bb0.w, 0.0f) * wp0.w +
               fmaxf(dnA * accA[4] + bb1.x, 0.0f) * wp1.x +
               fmaxf(dnA * accA[5] + bb1.y, 0.0f) * wp1.y +
               fmaxf(dnA * accA[6] + bb1.z, 0.0f) * wp1.z +
               fmaxf(dnA * accA[7] + bb1.w, 0.0f) * wp1.w;
    float sB = fmaxf(dnB * accB[0] + bb0.x, 0.0f) * wp0.x +
               fmaxf(dnB * accB[1] + bb0.y, 0.0f) * wp0.y +
               fmaxf(dnB * accB[2] + bb0.z, 0.0f) * wp0.z +
               fmaxf(dnB * accB[3] + bb0.w, 0.0f) * wp0.w +
               fmaxf(dnB * accB[4] + bb1.x, 0.0f) * wp1.x +
               fmaxf(dnB * accB[5] + bb1.y, 0.0f) * wp1.y +
               fmaxf(dnB * accB[6] + bb1.z, 0.0f) * wp1.z +
               fmaxf(dnB * accB[7] + bb1.w, 0.0f) * wp1.w;
    sA += __shfl_xor(sA, 1);
    sA += __shfl_xor(sA, 2);
    sA += __shfl_xor(sA, 4);
    sA += __shfl_xor(sA, 8);
    sB += __shfl_xor(sB, 1);
    sB += __shfl_xor(sB, 2);
    sB += __shfl_xor(sB, 4);
    sB += __shfl_xor(sB, 8);
    if (lane == 0) {
        atomicAdd(&pool[batch[nA]], sA);
        if (hasB) atomicAdd(&pool[batch[nB]], sB);
    }
}

// ---------------------------------------------------------------------------
// batch is sorted: per-graph node counts via binary search (replaces 100K
// float atomics previously done in gather2).
__global__ __launch_bounds__(256) void final_out_kernel(const float* __restrict__ pool,
                                                        const int* __restrict__ batch,
                                                        const float* __restrict__ bp,
                                                        float* __restrict__ out, int g) {
    int i = blockIdx.x * 256 + threadIdx.x;
    if (i >= g) return;
    int lo = 0, hi = NN;
    while (lo < hi) { int mid = (lo + hi) >> 1; if (batch[mid] < i) lo = mid + 1; else hi = mid; }
    int s0 = lo;
    hi = NN;
    while (lo < hi) { int mid = (lo + hi) >> 1; if (batch[mid] < i + 1) lo = mid + 1; else hi = mid; }
    float c = (float)(lo - s0);
    out[i] = pool[i] / fmaxf(c, 1.0f) + bp[0];
}

// ---------------------------------------------------------------------------
extern "C" void kernel_launch(void* const* d_in, const int* in_sizes, int n_in,
                              void* d_out, int out_size, void* d_ws, size_t ws_size,
                              hipStream_t stream) {
    const float* x     = (const float*)d_in[0];
    const int*   ei    = (const int*)d_in[1];   // [2, E]: src = ei[0:E], dst = ei[E:2E]
    const int*   batch = (const int*)d_in[2];
    const float* W1    = (const float*)d_in[3];
    const float* b1    = (const float*)d_in[4];
    const float* W2    = (const float*)d_in[5];
    const float* b2    = (const float*)d_in[6];
    const float* Wp    = (const float*)d_in[7];
    const float* bp    = (const float*)d_in[8];
    float* out = (float*)d_out;

    const int E = in_sizes[1] / 2;   // 1,600,000
    const int* src = ei;
    const int* dst = ei + E;

    // workspace layout
    const size_t BUFH = (size_t)NN * H * sizeof(_Float16);   // 25.6 MB
    const size_t NI   = 401408;                               // >= (NN+1)*4, 4KB-mult
    char* ws = (char*)d_ws;
    size_t off = 0;
    _Float16* tS   = (_Float16*)(ws + off); off += BUFH;     // GEMM1 out (fp16)
    _Float16* h1   = (_Float16*)(ws + off); off += BUFH;     // layer-1 acts (fp16)
    _Float16* tS2  = (_Float16*)(ws + off); off += BUFH;     // GEMM2 out (fp16)
    int*      deg  = (int*)     (ws + off); off += NI;
    int*   rowptr  = (int*)     (ws + off); off += NI;
    int*   cursor  = (int*)     (ws + off); off += NI;
    float*    dinv = (float*)   (ws + off); off += NI;
    int*      col  = (int*)     (ws + off); off += ((size_t)E * 4 + 4095) / 4096 * 4096;
    _Float16* Wt1  = (_Float16*)(ws + off); off += 32768;
    _Float16* Wt2  = (_Float16*)(ws + off); off += 32768;
    int*      bsum = (int*)     (ws + off); off += 4096;
    float*    pool = (float*)   (ws + off); off += 2048;

    const int NB  = (NN + 255) / 256;   // 391 scan blocks
    const int NFB = (E + 255) / 256;    // 6250 fill/hist blocks
    const int NGB = (NN + 63) / 64;     // 1563 gemm blocks
    const int NPB = (NN + 7) / 8;       // 12500 pair-gather blocks (8 nodes/block)

    // --- weights prep ∥ histogram (one dispatch), then scans ---
    hipMemsetAsync(deg, 0, NN * sizeof(int), stream);
    hipMemsetAsync(pool, 0, 2048, stream);
    k_wprep_hist<<<128 + NFB, 256, 0, stream>>>(W1, W2, Wt1, Wt2, dst, deg, E);
    k_scan_block<<<NB, 256, 0, stream>>>(deg, rowptr, bsum, NN);
    k_scan_top<<<1, 512, 0, stream>>>(bsum, NB);
    k_scan_fin<<<NB, 256, 0, stream>>>(rowptr, bsum, deg, cursor, dinv, NN, E);

    // --- fill CSR  ∥  GEMM1 (one dispatch, disjoint block ranges) ---
    k_fill_gemm1<<<NFB + NGB, 256, 0, stream>>>(src, dst, cursor, col, E, NFB,
                                                x, Wt1, dinv, tS, NN);

    // --- layer 1: pair-gather (wave/2 nodes) then LDS-free MFMA GEMM2 ---
    k_gather1<<<NPB, 256, 0, stream>>>(tS, rowptr, col, dinv, b1, h1, NN);
    k_gemm2<<<NGB, 256, 0, stream>>>(h1, Wt2, dinv, tS2, NN);

    // --- layer 2 pair-gather + pool head ---
    k_gather2<<<NPB, 256, 0, stream>>>(tS2, rowptr, col, dinv, b2, Wp,
                                       batch, pool, NN);

    // --- head ---
    final_out_kernel<<<(NG + 255) / 256, 256, 0, stream>>>(pool, batch, bp, out, NG);
}